// Round 13
// baseline (287.631 us; speedup 1.0000x reference)
//
#include <hip/hip_runtime.h>
#include <stdint.h>

typedef unsigned short ushort_t;
typedef __bf16 bf16x4 __attribute__((ext_vector_type(4)));
typedef __bf16 bf16x8 __attribute__((ext_vector_type(8)));
typedef float f32x4 __attribute__((ext_vector_type(4)));
typedef float f32x16 __attribute__((ext_vector_type(16)));
typedef unsigned short us8 __attribute__((ext_vector_type(8)));
typedef unsigned short us4v __attribute__((ext_vector_type(4)));

__device__ __forceinline__ float bf2f(ushort_t u) {
  union { uint32_t u; float f; } v; v.u = ((uint32_t)u) << 16; return v.f;
}
__device__ __forceinline__ ushort_t f2bf(float f) {
  union { float f; uint32_t u; } v; v.f = f;
  uint32_t u = v.u;
  uint32_t r = (u + 0x7FFFu + ((u >> 16) & 1u)) >> 16;  // RNE
  return (ushort_t)r;
}
__device__ __forceinline__ uint32_t pkbf(float a, float b) {
  __bf16 x = (__bf16)a, y = (__bf16)b;           // native RNE converts
  uint32_t ux = __builtin_bit_cast(unsigned short, x);
  uint32_t uy = __builtin_bit_cast(unsigned short, y);
  return ux | (uy << 16);
}
__device__ __forceinline__ void gload_lds16(const void* g, void* l) {
  __builtin_amdgcn_global_load_lds(
      (const __attribute__((address_space(1))) void*)g,
      (__attribute__((address_space(3))) void*)l, 16, 0, 0);
}
// ds_read_b64_tr_b16 (cross-lane transpose): 16-lane group, lane reads its
// own qword at base+(l&15)*8; delivers column (l&15) of the [4kv][16d] subtile.
__device__ __forceinline__ void tr2(const ushort_t* p, bf16x4& lo, bf16x4& hi) {
  asm volatile("ds_read_b64_tr_b16 %0, %2\n\t"
               "ds_read_b64_tr_b16 %1, %2 offset:128"
               : "=&v"(lo), "=&v"(hi)
               : "v"((const __attribute__((address_space(3))) ushort_t*)p));
}

template <typename T> __device__ __forceinline__ T to_out(float f);
template <> __device__ __forceinline__ ushort_t to_out<ushort_t>(float f) { return f2bf(f); }
template <> __device__ __forceinline__ float to_out<float>(float f) { return f; }

#define SCQ 0.1803368801111204f   /* 0.125 * log2(e) */

// ---------------------------------------------------------------------------
// fp32 -> bf16 convert, three inputs, static block partition.
// Blocks 1792+ also zero the attn completion flags (runs before attn_fwd on
// the stream every launch/replay -> deterministic protocol state).
// ---------------------------------------------------------------------------
__global__ void f2b3_kernel(const float* __restrict__ a, ushort_t* __restrict__ ao,
                            const float* __restrict__ b, ushort_t* __restrict__ bo,
                            const float* __restrict__ c, ushort_t* __restrict__ co,
                            int* __restrict__ flags) {
  int blk = blockIdx.x;
  const float* src; ushort_t* dst; int n4, b0, nb;
  if (blk < 1024)      { src = a; dst = ao; n4 = 1048576; b0 = blk;        nb = 1024; }
  else if (blk < 1792) { src = b; dst = bo; n4 = 786432;  b0 = blk - 1024; nb = 768; }
  else                 { src = c; dst = co; n4 = 262144;  b0 = blk - 1792; nb = 256;
                         if (threadIdx.x == 0) flags[blk - 1792] = 0; }
  for (int i = b0 * 256 + threadIdx.x; i < n4; i += nb * 256) {
    float4 v = ((const float4*)src)[i];
    us4v o;
    o[0] = f2bf(v.x); o[1] = f2bf(v.y); o[2] = f2bf(v.z); o[3] = f2bf(v.w);
    ((us4v*)dst)[i] = o;
  }
}

// ---------------------------------------------------------------------------
// GEMM: C[M][N] = A[M][K] @ W[N][K]^T (+bias), bf16 in, fp32 accum, OT out.
// SCALEQ: multiply output cols < 1024 by SCQ (Q-prescale for attn).
// T1 XCD swizzle: bijective blockIdx remap (nwg % 8 == 0).
// ---------------------------------------------------------------------------
template<bool BIAS, typename OT, bool SCALEQ>
__global__ __launch_bounds__(256, 2) void gemm_bt(
    const ushort_t* __restrict__ A, const ushort_t* __restrict__ W,
    const float* __restrict__ bias, OT* __restrict__ C,
    int M, int N, int K)
{
  __shared__ ushort_t As[128 * 64];
  __shared__ ushort_t Bs[128 * 64];
  const int t = threadIdx.x;
  const int w = t >> 6, lane = t & 63;
  const int lg = lane >> 4, lc = lane & 15;

  const int NX = N >> 7;
  const int nwg = gridDim.x;
  const int o = blockIdx.x;
  const int id = (o & 7) * (nwg >> 3) + (o >> 3);
  const int rowbase = (id / NX) * 128;
  const int colbase = (id % NX) * 128;
  const int wr = (w >> 1) * 64, wc = (w & 1) * 64;

  f32x4 acc[4][4] = {};
  const int nkt = K >> 6;

  for (int kt = 0; kt < nkt; ++kt) {
#pragma unroll
    for (int i = 0; i < 4; ++i) {
      int off = (i * 256 + t) * 16;
      int row = off >> 7;
      int cb  = off & 127;
      int ec  = cb ^ ((row & 7) << 4);
      gload_lds16(A + (size_t)(rowbase + row) * K + kt * 64 + (ec >> 1),
                  (char*)As + off);
      gload_lds16(W + (size_t)(colbase + row) * K + kt * 64 + (ec >> 1),
                  (char*)Bs + off);
    }
    __syncthreads();
#pragma unroll
    for (int kk = 0; kk < 2; ++kk) {
      bf16x8 af[4], bf[4];
#pragma unroll
      for (int m = 0; m < 4; ++m) {
        int row = wr + m * 16 + lc;
        int kb  = (lg * 16 + kk * 64) ^ ((row & 7) << 4);
        af[m] = *(const bf16x8*)((const char*)As + row * 128 + kb);
        int col = wc + m * 16 + lc;
        int kb2 = (lg * 16 + kk * 64) ^ ((col & 7) << 4);
        bf[m] = *(const bf16x8*)((const char*)Bs + col * 128 + kb2);
      }
#pragma unroll
      for (int m = 0; m < 4; ++m)
#pragma unroll
        for (int n = 0; n < 4; ++n)
          acc[m][n] = __builtin_amdgcn_mfma_f32_16x16x32_bf16(af[m], bf[n],
                                                              acc[m][n], 0, 0, 0);
    }
    __syncthreads();
  }

#pragma unroll
  for (int m = 0; m < 4; ++m) {
    int r0 = rowbase + wr + m * 16 + lg * 4;
#pragma unroll
    for (int n = 0; n < 4; ++n) {
      int c0 = colbase + wc + n * 16 + lc;
      float bv = 0.f;
      if (BIAS) bv = bias[c0];
      float qs = 1.f;
      if (SCALEQ) qs = (c0 < 1024) ? SCQ : 1.f;
#pragma unroll
      for (int j = 0; j < 4; ++j)
        C[(size_t)(r0 + j) * N + c0] = to_out<OT>(acc[m][n][j] * qs + bv);
    }
  }
}

// ---------------------------------------------------------------------------
// Flash attention v10: r12 body + IN-KERNEL SPLIT MERGE. The two KV-split
// blocks of a (qt,bh) pair share an XCD (same L2); each writes its
// unnormalized bf16 partial + l, fences, bumps a flag; the SECOND finisher
// reads the other partial and writes the merged result to o1. Merge math is
// (bf16(O1)+bf16(O2))*inv -- own accumulators rounded through bf16 first, so
// the result is bit-identical regardless of completion order (deterministic,
// same as the old merge_kernel).
// ---------------------------------------------------------------------------
__global__ __launch_bounds__(512, 4) void attn_fwd(
    const ushort_t* __restrict__ qkv, ushort_t* __restrict__ o1,
    ushort_t* __restrict__ o2, float* __restrict__ lbuf,
    int* __restrict__ flags)
{
  __shared__ ushort_t Ks[2][64 * 64];
  __shared__ ushort_t Vs[2][64 * 64];

  const int t = threadIdx.x, w = t >> 6, lane = t & 63;
  const int l31 = lane & 31, hi = lane >> 5;
  const int lc = lane & 15;

  // bijective decode: xcd = d&7, qt = (d>>3)&7, bhs = xcd*8 + (d>>6)
  // pair members (split 0/1) have consecutive bhs -> same xcd -> same L2.
  const int d = blockIdx.x;
  const int qt = (d >> 3) & 7;
  const int bhs = (d & 7) * 8 + (d >> 6);
  const int bh = bhs >> 1, split = bhs & 1;
  const int b = bh >> 4, h = bh & 15;

  const ushort_t* Qg = qkv + (size_t)(b * 2048) * 3072 + h * 64;
  const ushort_t* Kg = Qg + 1024 + (size_t)split * 1024 * 3072;
  const ushort_t* Vg = Qg + 2048 + (size_t)split * 1024 * 3072;

  auto stage_k = [&](ushort_t* Kd, int kt) {
    int off = t * 16;
    int row = off >> 7;
    int cb  = off & 127;
    int ec  = cb ^ ((row & 7) << 4);
    gload_lds16(Kg + (size_t)(kt * 64 + row) * 3072 + (ec >> 1),
                (char*)Kd + off);
  };
  const int vr  = t >> 3;
  const int vc0 = (t & 7) * 8;
  const int vdst = (vc0 >> 4) * 2048 + (vr >> 2) * 128 + (vr & 3) * 32 +
                   (vc0 & 8) * 2;

  // ---- Q fragments (B-operand): lane -> Q[q=l31][d = kk*16+hi*8+e] ----
  const ushort_t* qrow_p = Qg + (size_t)(qt * 256 + w * 32 + l31) * 3072;
  bf16x8 qf[4];
#pragma unroll
  for (int kk = 0; kk < 4; ++kk)
    qf[kk] = *(const bf16x8*)(qrow_p + kk * 16 + hi * 8);

  // ---- prologue staging ----
  stage_k(Ks[0], 0);
  {
    us8 v = *(const us8*)(Vg + (size_t)vr * 3072 + vc0);
    *(us8*)((char*)Vs[0] + vdst) = v;
  }
  __syncthreads();

  f32x16 oacc0 = {}, oacc1 = {};
  float l = 0.f;
  const int m16 = (lane >> 4) & 1;

  int cur = 0;
  for (int kt = 0; kt < 16; ++kt) {
    // ---- issue next tile's loads early ----
    us8 vnext;
    if (kt < 15) {
      stage_k(Ks[cur ^ 1], kt + 1);
      vnext = *(const us8*)(Vg + (size_t)((kt + 1) * 64 + vr) * 3072 + vc0);
    }

    // ---- S^T = K @ Q'^T (Q pre-scaled by SCQ) ----
    const ushort_t* Kc = Ks[cur];
    f32x16 s0 = {}, s1 = {};
    __builtin_amdgcn_s_setprio(1);
#pragma unroll
    for (int kk = 0; kk < 4; ++kk) {
      int cbyte = (kk * 32 + hi * 16);
      int r0 = l31, r1 = 32 + l31;
      bf16x8 kf0 = *(const bf16x8*)((const char*)Kc + r0 * 128 +
                                    (cbyte ^ ((r0 & 7) << 4)));
      bf16x8 kf1 = *(const bf16x8*)((const char*)Kc + r1 * 128 +
                                    (cbyte ^ ((r1 & 7) << 4)));
      s0 = __builtin_amdgcn_mfma_f32_32x32x16_bf16(kf0, qf[kk], s0, 0, 0, 0);
      s1 = __builtin_amdgcn_mfma_f32_32x32x16_bf16(kf1, qf[kk], s1, 0, 0, 0);
    }
    __builtin_amdgcn_s_setprio(0);

    // ---- max-free softmax: P = exp2(s) (bounded; Q carries the scale) ----
#pragma unroll
    for (int i = 0; i < 16; ++i) {
      s0[i] = __builtin_amdgcn_exp2f(s0[i]);
      s1[i] = __builtin_amdgcn_exp2f(s1[i]);
    }
    float rs = (((s0[0] + s0[1]) + (s0[2] + s0[3])) +
                ((s0[4] + s0[5]) + (s0[6] + s0[7]))) +
               (((s0[8] + s0[9]) + (s0[10] + s0[11])) +
                ((s0[12] + s0[13]) + (s0[14] + s0[15])));
    float rt = (((s1[0] + s1[1]) + (s1[2] + s1[3])) +
                ((s1[4] + s1[5]) + (s1[6] + s1[7]))) +
               (((s1[8] + s1[9]) + (s1[10] + s1[11])) +
                ((s1[12] + s1[13]) + (s1[14] + s1[15])));
    l += rs + rt;

    // ---- P -> bf16 dwords (pairs of consecutive r) ----
    uint32_t pk0[8], pk1[8];
#pragma unroll
    for (int j = 0; j < 8; ++j) {
      pk0[j] = pkbf(s0[2 * j], s0[2 * j + 1]);
      pk1[j] = pkbf(s1[2 * j], s1[2 * j + 1]);
    }

    // ---- write next V tile ----
    if (kt < 15)
      *(us8*)((char*)Vs[cur ^ 1] + vdst) = vnext;

    // ---- build PV operands: pa via permlane32_swap, vf via tr_read ----
    const ushort_t* Vc = Vs[cur];
    bf16x8 pa[4], vf[4][2];
#pragma unroll
    for (int ks = 0; ks < 4; ++ks) {
      int j0 = 4 * (ks & 1);
      uint32_t x0 = (ks < 2) ? pk0[j0]     : pk1[j0];
      uint32_t x1 = (ks < 2) ? pk0[j0 + 1] : pk1[j0 + 1];
      uint32_t y0 = (ks < 2) ? pk0[j0 + 2] : pk1[j0 + 2];
      uint32_t y1 = (ks < 2) ? pk0[j0 + 3] : pk1[j0 + 3];
      asm volatile("v_permlane32_swap_b32 %0, %1" : "+v"(x0), "+v"(y0));
      asm volatile("v_permlane32_swap_b32 %0, %1" : "+v"(x1), "+v"(y1));
      union { uint32_t du[4]; bf16x8 v; } U;
      U.du[0] = x0; U.du[1] = x1; U.du[2] = y0; U.du[3] = y1;
      pa[ks] = U.v;
#pragma unroll
      for (int nd = 0; nd < 2; ++nd) {
        bf16x4 lo, hh;
        tr2(Vc + (nd * 2 + m16) * 1024 + (4 * ks + 2 * hi) * 64 + lc * 4, lo, hh);
        vf[ks][nd] = __builtin_shufflevector(lo, hh, 0, 1, 2, 3, 4, 5, 6, 7);
      }
    }
    asm volatile("s_waitcnt lgkmcnt(0)" ::: "memory");  // rule #18
    __builtin_amdgcn_sched_barrier(0);
    __builtin_amdgcn_s_setprio(1);
#pragma unroll
    for (int ks = 0; ks < 4; ++ks) {
      oacc0 = __builtin_amdgcn_mfma_f32_32x32x16_bf16(pa[ks], vf[ks][0], oacc0, 0, 0, 0);
      oacc1 = __builtin_amdgcn_mfma_f32_32x32x16_bf16(pa[ks], vf[ks][1], oacc1, 0, 0, 0);
    }
    __builtin_amdgcn_s_setprio(0);

    __syncthreads();   // drains staging; protects double buffers
    cur ^= 1;
  }

  // ---- deferred cross-half l reduce ----
  l += __shfl_xor(l, 32);

  // ---- write own unnormalized partial + l ----
  ushort_t* op = split ? o2 : o1;
  const int qrow0 = qt * 256 + w * 32;
#pragma unroll
  for (int r = 0; r < 16; ++r) {
    int crow = (r & 3) + 8 * (r >> 2) + 4 * hi;
    size_t base = ((size_t)(b * 2048 + qrow0 + crow)) * 1024 + h * 64 + l31;
    op[base]      = f2bf(oacc0[r]);
    op[base + 32] = f2bf(oacc1[r]);
  }
  if (hi == 0)
    lbuf[(size_t)split * 65536 + (size_t)(b * 2048 + qrow0 + l31) * 16 + h] = l;

  // ---- completion protocol: second finisher merges (same-XCD pair) ----
  __threadfence();
  __syncthreads();
  __shared__ int s_old;
  if (t == 0) s_old = atomicAdd(&flags[bh * 8 + qt], 1);
  __syncthreads();
  if (s_old == 1) {
    __threadfence();
    const ushort_t* other = split ? o1 : o2;
    float lo = lbuf[(size_t)(split ^ 1) * 65536 +
                    (size_t)(b * 2048 + qrow0 + l31) * 16 + h];
    float linv = 1.f / (l + lo);
#pragma unroll
    for (int r = 0; r < 16; ++r) {
      int crow = (r & 3) + 8 * (r >> 2) + 4 * hi;
      float iq = __shfl(linv, crow);
      size_t base = ((size_t)(b * 2048 + qrow0 + crow)) * 1024 + h * 64 + l31;
      // own acc rounded through bf16 -> order-independent, == old merge_kernel
      o1[base]      = f2bf((bf2f(f2bf(oacc0[r])) + bf2f(other[base])) * iq);
      o1[base + 32] = f2bf((bf2f(f2bf(oacc1[r])) + bf2f(other[base + 32])) * iq);
    }
  }
}

// ---------------------------------------------------------------------------
extern "C" void kernel_launch(void* const* d_in, const int* in_sizes, int n_in,
                              void* d_out, int out_size, void* d_ws, size_t ws_size,
                              hipStream_t stream) {
  const float* x     = (const float*)d_in[0];   // [2,2048,1024] fp32
  const float* Wqkv  = (const float*)d_in[1];   // [3072,1024] fp32
  const float* Wproj = (const float*)d_in[2];   // [1024,1024] fp32
  const float* bproj = (const float*)d_in[3];   // [1024] fp32
  float* out = (float*)d_out;                   // [4096,1024] fp32

  ushort_t* qkv   = (ushort_t*)d_ws;                    // [4096,3072] bf16
  ushort_t* o1    = qkv   + (size_t)4096 * 3072;        // [4096,1024] bf16 (O1/final)
  ushort_t* xb    = o1    + (size_t)4096 * 1024;        // [4096,1024] bf16 (x, then O2)
  ushort_t* wqb   = xb    + (size_t)4096 * 1024;        // [3072,1024] bf16
  ushort_t* wpb   = wqb   + (size_t)3072 * 1024;        // [1024,1024] bf16
  float*    lbuf  = (float*)(wpb + (size_t)1024 * 1024); // [2][4096][16] float
  int*      flags = (int*)(lbuf + (size_t)2 * 65536);    // [256] int

  dim3 blk(256);
  f2b3_kernel<<<2048, blk, 0, stream>>>(x, xb, Wqkv, wqb, Wproj, wpb, flags);

  gemm_bt<false, ushort_t, true><<<768, blk, 0, stream>>>(
      xb, wqb, nullptr, qkv, 4096, 3072, 1024);
  attn_fwd<<<dim3(512), dim3(512), 0, stream>>>(qkv, o1, xb, lbuf, flags);
  gemm_bt<true, float, false><<<256, blk, 0, stream>>>(
      o1, wpb, bproj, out, 4096, 1024, 1024);
}

// Round 14
// 109.268 us; speedup vs baseline: 2.6324x; 2.6324x over previous
//
#include <hip/hip_runtime.h>
#include <stdint.h>

typedef unsigned short ushort_t;
typedef __bf16 bf16x4 __attribute__((ext_vector_type(4)));
typedef __bf16 bf16x8 __attribute__((ext_vector_type(8)));
typedef float f32x4 __attribute__((ext_vector_type(4)));
typedef float f32x16 __attribute__((ext_vector_type(16)));
typedef unsigned short us8 __attribute__((ext_vector_type(8)));
typedef unsigned short us4v __attribute__((ext_vector_type(4)));

__device__ __forceinline__ float bf2f(ushort_t u) {
  union { uint32_t u; float f; } v; v.u = ((uint32_t)u) << 16; return v.f;
}
__device__ __forceinline__ ushort_t f2bf(float f) {
  union { float f; uint32_t u; } v; v.f = f;
  uint32_t u = v.u;
  uint32_t r = (u + 0x7FFFu + ((u >> 16) & 1u)) >> 16;  // RNE
  return (ushort_t)r;
}
// hardware packed bf16 convert (RNE): dst = {lo: bf16(a), hi: bf16(b)}
__device__ __forceinline__ uint32_t cvtpk(float a, float b) {
  uint32_t r;
  asm("v_cvt_pk_bf16_f32 %0, %1, %2" : "=v"(r) : "v"(a), "v"(b));
  return r;
}
__device__ __forceinline__ void gload_lds16(const void* g, void* l) {
  __builtin_amdgcn_global_load_lds(
      (const __attribute__((address_space(1))) void*)g,
      (__attribute__((address_space(3))) void*)l, 16, 0, 0);
}
// ds_read_b64_tr_b16 (cross-lane transpose): 16-lane group, lane reads its
// own qword at base+(l&15)*8; delivers column (l&15) of the [4kv][16d] subtile.
__device__ __forceinline__ void tr2(const ushort_t* p, bf16x4& lo, bf16x4& hi) {
  asm volatile("ds_read_b64_tr_b16 %0, %2\n\t"
               "ds_read_b64_tr_b16 %1, %2 offset:128"
               : "=&v"(lo), "=&v"(hi)
               : "v"((const __attribute__((address_space(3))) ushort_t*)p));
}

template <typename T> __device__ __forceinline__ T to_out(float f);
template <> __device__ __forceinline__ ushort_t to_out<ushort_t>(float f) { return f2bf(f); }
template <> __device__ __forceinline__ float to_out<float>(float f) { return f; }

#define SCQ 0.1803368801111204f   /* 0.125 * log2(e) */

// ---------------------------------------------------------------------------
// fp32 -> bf16 convert, three inputs, static block partition
// ---------------------------------------------------------------------------
__global__ void f2b3_kernel(const float* __restrict__ a, ushort_t* __restrict__ ao,
                            const float* __restrict__ b, ushort_t* __restrict__ bo,
                            const float* __restrict__ c, ushort_t* __restrict__ co) {
  int blk = blockIdx.x;
  const float* src; ushort_t* dst; int n4, b0, nb;
  if (blk < 1024)      { src = a; dst = ao; n4 = 1048576; b0 = blk;        nb = 1024; }
  else if (blk < 1792) { src = b; dst = bo; n4 = 786432;  b0 = blk - 1024; nb = 768; }
  else                 { src = c; dst = co; n4 = 262144;  b0 = blk - 1792; nb = 256; }
  for (int i = b0 * 256 + threadIdx.x; i < n4; i += nb * 256) {
    float4 v = ((const float4*)src)[i];
    us4v o;
    o[0] = f2bf(v.x); o[1] = f2bf(v.y); o[2] = f2bf(v.z); o[3] = f2bf(v.w);
    ((us4v*)dst)[i] = o;
  }
}

// ---------------------------------------------------------------------------
// GEMM: C[M][N] = A[M][K] @ W[N][K]^T (+bias), bf16 in, fp32 accum, OT out.
// SCALEQ: multiply output cols < 1024 by SCQ (Q-prescale for attn).
// T1 XCD swizzle: bijective blockIdx remap (nwg % 8 == 0).
// ---------------------------------------------------------------------------
template<bool BIAS, typename OT, bool SCALEQ>
__global__ __launch_bounds__(256, 2) void gemm_bt(
    const ushort_t* __restrict__ A, const ushort_t* __restrict__ W,
    const float* __restrict__ bias, OT* __restrict__ C,
    int M, int N, int K)
{
  __shared__ ushort_t As[128 * 64];
  __shared__ ushort_t Bs[128 * 64];
  const int t = threadIdx.x;
  const int w = t >> 6, lane = t & 63;
  const int lg = lane >> 4, lc = lane & 15;

  const int NX = N >> 7;
  const int nwg = gridDim.x;
  const int o = blockIdx.x;
  const int id = (o & 7) * (nwg >> 3) + (o >> 3);
  const int rowbase = (id / NX) * 128;
  const int colbase = (id % NX) * 128;
  const int wr = (w >> 1) * 64, wc = (w & 1) * 64;

  f32x4 acc[4][4] = {};
  const int nkt = K >> 6;

  for (int kt = 0; kt < nkt; ++kt) {
#pragma unroll
    for (int i = 0; i < 4; ++i) {
      int off = (i * 256 + t) * 16;
      int row = off >> 7;
      int cb  = off & 127;
      int ec  = cb ^ ((row & 7) << 4);
      gload_lds16(A + (size_t)(rowbase + row) * K + kt * 64 + (ec >> 1),
                  (char*)As + off);
      gload_lds16(W + (size_t)(colbase + row) * K + kt * 64 + (ec >> 1),
                  (char*)Bs + off);
    }
    __syncthreads();
#pragma unroll
    for (int kk = 0; kk < 2; ++kk) {
      bf16x8 af[4], bf[4];
#pragma unroll
      for (int m = 0; m < 4; ++m) {
        int row = wr + m * 16 + lc;
        int kb  = (lg * 16 + kk * 64) ^ ((row & 7) << 4);
        af[m] = *(const bf16x8*)((const char*)As + row * 128 + kb);
        int col = wc + m * 16 + lc;
        int kb2 = (lg * 16 + kk * 64) ^ ((col & 7) << 4);
        bf[m] = *(const bf16x8*)((const char*)Bs + col * 128 + kb2);
      }
#pragma unroll
      for (int m = 0; m < 4; ++m)
#pragma unroll
        for (int n = 0; n < 4; ++n)
          acc[m][n] = __builtin_amdgcn_mfma_f32_16x16x32_bf16(af[m], bf[n],
                                                              acc[m][n], 0, 0, 0);
    }
    __syncthreads();
  }

#pragma unroll
  for (int m = 0; m < 4; ++m) {
    int r0 = rowbase + wr + m * 16 + lg * 4;
#pragma unroll
    for (int n = 0; n < 4; ++n) {
      int c0 = colbase + wc + n * 16 + lc;
      float bv = 0.f;
      if (BIAS) bv = bias[c0];
      float qs = 1.f;
      if (SCALEQ) qs = (c0 < 1024) ? SCQ : 1.f;
#pragma unroll
      for (int j = 0; j < 4; ++j)
        C[(size_t)(r0 + j) * N + c0] = to_out<OT>(acc[m][n][j] * qs + bv);
    }
  }
}

// ---------------------------------------------------------------------------
// Flash attention v11 (r12 structure + VALU trims): 8 waves/512 thr, q-tile
// 256, KV-split(2), 16 iters kv64, max-free softmax (Q pre-scaled by SCQ).
// New: P-pack via v_cvt_pk_bf16_f32 (1 op vs ~4); row-sum l computed on the
// MFMA pipe via B=ones (lacc = mfma(pa, ones)) instead of a 30-add VALU tree.
// Partials unnormalized bf16 + l (now summed over bf16 P -- consistent with
// the numerator). Merged by merge_kernel (separate, L2-safe).
// ---------------------------------------------------------------------------
__global__ __launch_bounds__(512, 4) void attn_fwd(
    const ushort_t* __restrict__ qkv, ushort_t* __restrict__ o1,
    ushort_t* __restrict__ o2, float* __restrict__ lbuf)
{
  __shared__ ushort_t Ks[2][64 * 64];
  __shared__ ushort_t Vs[2][64 * 64];

  const int t = threadIdx.x, w = t >> 6, lane = t & 63;
  const int l31 = lane & 31, hi = lane >> 5;
  const int lc = lane & 15;

  // bijective decode: xcd = d&7, qt = (d>>3)&7, bhs = xcd*8 + (d>>6)
  const int d = blockIdx.x;
  const int qt = (d >> 3) & 7;
  const int bhs = (d & 7) * 8 + (d >> 6);
  const int bh = bhs >> 1, split = bhs & 1;
  const int b = bh >> 4, h = bh & 15;

  const ushort_t* Qg = qkv + (size_t)(b * 2048) * 3072 + h * 64;
  const ushort_t* Kg = Qg + 1024 + (size_t)split * 1024 * 3072;
  const ushort_t* Vg = Qg + 2048 + (size_t)split * 1024 * 3072;

  auto stage_k = [&](ushort_t* Kd, int kt) {
    int off = t * 16;
    int row = off >> 7;
    int cb  = off & 127;
    int ec  = cb ^ ((row & 7) << 4);
    gload_lds16(Kg + (size_t)(kt * 64 + row) * 3072 + (ec >> 1),
                (char*)Kd + off);
  };
  const int vr  = t >> 3;
  const int vc0 = (t & 7) * 8;
  const int vdst = (vc0 >> 4) * 2048 + (vr >> 2) * 128 + (vr & 3) * 32 +
                   (vc0 & 8) * 2;

  // ---- Q fragments (B-operand): lane -> Q[q=l31][d = kk*16+hi*8+e] ----
  const ushort_t* qrow_p = Qg + (size_t)(qt * 256 + w * 32 + l31) * 3072;
  bf16x8 qf[4];
#pragma unroll
  for (int kk = 0; kk < 4; ++kk)
    qf[kk] = *(const bf16x8*)(qrow_p + kk * 16 + hi * 8);

  // ---- all-ones B fragment for the MFMA row-sum ----
  bf16x8 ones;
#pragma unroll
  for (int i = 0; i < 8; ++i) ones[i] = (__bf16)1.0f;

  // ---- prologue staging ----
  stage_k(Ks[0], 0);
  {
    us8 v = *(const us8*)(Vg + (size_t)vr * 3072 + vc0);
    *(us8*)((char*)Vs[0] + vdst) = v;
  }
  __syncthreads();

  f32x16 oacc0 = {}, oacc1 = {}, lacc = {};
  const int m16 = (lane >> 4) & 1;

  int cur = 0;
  for (int kt = 0; kt < 16; ++kt) {
    // ---- issue next tile's loads early ----
    us8 vnext;
    if (kt < 15) {
      stage_k(Ks[cur ^ 1], kt + 1);
      vnext = *(const us8*)(Vg + (size_t)((kt + 1) * 64 + vr) * 3072 + vc0);
    }

    // ---- S^T = K @ Q'^T (Q pre-scaled by SCQ) ----
    const ushort_t* Kc = Ks[cur];
    f32x16 s0 = {}, s1 = {};
    __builtin_amdgcn_s_setprio(1);
#pragma unroll
    for (int kk = 0; kk < 4; ++kk) {
      int cbyte = (kk * 32 + hi * 16);
      int r0 = l31, r1 = 32 + l31;
      bf16x8 kf0 = *(const bf16x8*)((const char*)Kc + r0 * 128 +
                                    (cbyte ^ ((r0 & 7) << 4)));
      bf16x8 kf1 = *(const bf16x8*)((const char*)Kc + r1 * 128 +
                                    (cbyte ^ ((r1 & 7) << 4)));
      s0 = __builtin_amdgcn_mfma_f32_32x32x16_bf16(kf0, qf[kk], s0, 0, 0, 0);
      s1 = __builtin_amdgcn_mfma_f32_32x32x16_bf16(kf1, qf[kk], s1, 0, 0, 0);
    }
    __builtin_amdgcn_s_setprio(0);

    // ---- max-free softmax: P = exp2(s) (bounded; Q carries the scale) ----
#pragma unroll
    for (int i = 0; i < 16; ++i) {
      s0[i] = __builtin_amdgcn_exp2f(s0[i]);
      s1[i] = __builtin_amdgcn_exp2f(s1[i]);
    }

    // ---- P -> bf16 dwords via hardware cvt_pk (pairs of consecutive r) ----
    uint32_t pk0[8], pk1[8];
#pragma unroll
    for (int j = 0; j < 8; ++j) {
      pk0[j] = cvtpk(s0[2 * j], s0[2 * j + 1]);
      pk1[j] = cvtpk(s1[2 * j], s1[2 * j + 1]);
    }

    // ---- write next V tile ----
    if (kt < 15)
      *(us8*)((char*)Vs[cur ^ 1] + vdst) = vnext;

    // ---- build PV operands: pa via permlane32_swap, vf via tr_read ----
    const ushort_t* Vc = Vs[cur];
    bf16x8 pa[4], vf[4][2];
#pragma unroll
    for (int ks = 0; ks < 4; ++ks) {
      int j0 = 4 * (ks & 1);
      uint32_t x0 = (ks < 2) ? pk0[j0]     : pk1[j0];
      uint32_t x1 = (ks < 2) ? pk0[j0 + 1] : pk1[j0 + 1];
      uint32_t y0 = (ks < 2) ? pk0[j0 + 2] : pk1[j0 + 2];
      uint32_t y1 = (ks < 2) ? pk0[j0 + 3] : pk1[j0 + 3];
      asm volatile("v_permlane32_swap_b32 %0, %1" : "+v"(x0), "+v"(y0));
      asm volatile("v_permlane32_swap_b32 %0, %1" : "+v"(x1), "+v"(y1));
      union { uint32_t du[4]; bf16x8 v; } U;
      U.du[0] = x0; U.du[1] = x1; U.du[2] = y0; U.du[3] = y1;
      pa[ks] = U.v;
#pragma unroll
      for (int nd = 0; nd < 2; ++nd) {
        bf16x4 lo, hh;
        tr2(Vc + (nd * 2 + m16) * 1024 + (4 * ks + 2 * hi) * 64 + lc * 4, lo, hh);
        vf[ks][nd] = __builtin_shufflevector(lo, hh, 0, 1, 2, 3, 4, 5, 6, 7);
      }
    }
    asm volatile("s_waitcnt lgkmcnt(0)" ::: "memory");  // rule #18
    __builtin_amdgcn_sched_barrier(0);
    __builtin_amdgcn_s_setprio(1);
#pragma unroll
    for (int ks = 0; ks < 4; ++ks) {
      oacc0 = __builtin_amdgcn_mfma_f32_32x32x16_bf16(pa[ks], vf[ks][0], oacc0, 0, 0, 0);
      oacc1 = __builtin_amdgcn_mfma_f32_32x32x16_bf16(pa[ks], vf[ks][1], oacc1, 0, 0, 0);
      lacc  = __builtin_amdgcn_mfma_f32_32x32x16_bf16(pa[ks], ones, lacc, 0, 0, 0);
    }
    __builtin_amdgcn_s_setprio(0);

    __syncthreads();   // drains staging; protects double buffers
    cur ^= 1;
  }

  // ---- epilogue: unnormalized partial O + row-sum l (from lacc) ----
  ushort_t* op = split ? o2 : o1;
  const int qrow0 = qt * 256 + w * 32;
#pragma unroll
  for (int r = 0; r < 16; ++r) {
    int crow = (r & 3) + 8 * (r >> 2) + 4 * hi;
    size_t base = ((size_t)(b * 2048 + qrow0 + crow)) * 1024 + h * 64 + l31;
    op[base]      = f2bf(oacc0[r]);
    op[base + 32] = f2bf(oacc1[r]);
  }
  // lacc[r] = l[q=crow(r,hi)], replicated across all 32 columns (l31)
  if (l31 == 0) {
#pragma unroll
    for (int r = 0; r < 16; ++r) {
      int crow = (r & 3) + 8 * (r >> 2) + 4 * hi;
      lbuf[(size_t)split * 65536 +
           (size_t)(b * 2048 + qrow0 + crow) * 16 + h] = lacc[r];
    }
  }
}

// ---------------------------------------------------------------------------
// merge: o1 = (o1 + o2) / (l1 + l2), in-place (max-free partials).
// ---------------------------------------------------------------------------
__global__ void merge_kernel(ushort_t* __restrict__ o1,
                             const ushort_t* __restrict__ o2,
                             const float* __restrict__ lbuf) {
  int i = blockIdx.x * blockDim.x + threadIdx.x;
  int row = i >> 7;
  int col = (i & 127) * 8;
  int h = col >> 6;
  float l1 = lbuf[(size_t)row * 16 + h];
  float l2 = lbuf[65536 + (size_t)row * 16 + h];
  float inv = 1.f / (l1 + l2);
  us8 v1 = ((const us8*)o1)[i];
  us8 v2 = ((const us8*)o2)[i];
  us8 o;
#pragma unroll
  for (int j = 0; j < 8; ++j)
    o[j] = f2bf((bf2f(v1[j]) + bf2f(v2[j])) * inv);
  ((us8*)o1)[i] = o;
}

// ---------------------------------------------------------------------------
extern "C" void kernel_launch(void* const* d_in, const int* in_sizes, int n_in,
                              void* d_out, int out_size, void* d_ws, size_t ws_size,
                              hipStream_t stream) {
  const float* x     = (const float*)d_in[0];   // [2,2048,1024] fp32
  const float* Wqkv  = (const float*)d_in[1];   // [3072,1024] fp32
  const float* Wproj = (const float*)d_in[2];   // [1024,1024] fp32
  const float* bproj = (const float*)d_in[3];   // [1024] fp32
  float* out = (float*)d_out;                   // [4096,1024] fp32

  ushort_t* qkv   = (ushort_t*)d_ws;                    // [4096,3072] bf16
  ushort_t* o1    = qkv   + (size_t)4096 * 3072;        // [4096,1024] bf16 (O1/merged)
  ushort_t* xb    = o1    + (size_t)4096 * 1024;        // [4096,1024] bf16 (x, then O2)
  ushort_t* wqb   = xb    + (size_t)4096 * 1024;        // [3072,1024] bf16
  ushort_t* wpb   = wqb   + (size_t)3072 * 1024;        // [1024,1024] bf16
  float*    lbuf  = (float*)(wpb + (size_t)1024 * 1024); // [2][4096][16] float

  dim3 blk(256);
  f2b3_kernel<<<2048, blk, 0, stream>>>(x, xb, Wqkv, wqb, Wproj, wpb);

  gemm_bt<false, ushort_t, true><<<768, blk, 0, stream>>>(
      xb, wqb, nullptr, qkv, 4096, 3072, 1024);
  attn_fwd<<<dim3(512), dim3(512), 0, stream>>>(qkv, o1, xb, lbuf);
  merge_kernel<<<2048, blk, 0, stream>>>(o1, xb, lbuf);
  gemm_bt<true, float, false><<<256, blk, 0, stream>>>(
      o1, wpb, bproj, out, 4096, 1024, 1024);
}